// Round 5
// baseline (101.682 us; speedup 1.0000x reference)
//
#include <hip/hip_runtime.h>
#include <math.h>

#define NB 4
#define NL1 512
#define NL2 512
#define NKD 256
#define NA 128
#define NV 256

// output layout (floats): o1 [B,L2,V], o2 [B,L1,V], w1 [B,L2,L1], w2 [B,L1,L2], score [B,L1,L2]
#define O1_OFF 0
#define O2_OFF (NB*NL2*NV)                 // 524288
#define W1_OFF (O2_OFF + NB*NL1*NV)        // 1048576
#define W2_OFF (W1_OFF + NB*NL2*NL1)       // 2097152
#define SC_OFF (W2_OFF + NB*NL1*NL2)       // 3145728

// masked score positions use -1e30f, NOT -inf (harness absmax: (-inf)-(-inf)=nan fails).
#define MASK_NEG (-1e30f)

// p1/p2 are pre-scaled by 2*log2(e) so e^{2z} = 2^{p1'+p2'}
#define SC2LOG2E 2.8853900817779268f

#if __has_builtin(__builtin_amdgcn_exp2f)
#define EXP2F(x) __builtin_amdgcn_exp2f(x)
#else
#define EXP2F(x) __expf((x) * 0.6931471805599453f)
#endif
#if __has_builtin(__builtin_amdgcn_rcpf)
#define RCPF(x) __builtin_amdgcn_rcpf(x)
#else
#define RCPF(x) (1.0f / (x))
#endif

// ---------------- projection: p = SC2LOG2E * (K @ W + b) ----------------
__global__ __launch_bounds__(128) void proj_kernel(
    const float* __restrict__ k1, const float* __restrict__ k2,
    const float* __restrict__ W1, const float* __restrict__ b1,
    const float* __restrict__ W2, const float* __restrict__ b2,
    float* __restrict__ p1, float* __restrict__ p2)
{
    __shared__ float kr[4][NKD];
    int blk = blockIdx.x;
    int tid = threadIdx.x;
    const float *K, *W, *bias; float* P; int rowbase;
    if (blk < (NB*NL1)/4) { K = k1; W = W1; bias = b1; P = p1; rowbase = blk*4; }
    else                  { K = k2; W = W2; bias = b2; P = p2; rowbase = (blk - (NB*NL1)/4)*4; }
    for (int idx = tid; idx < 256; idx += 128) {
        int r = idx >> 6, c = idx & 63;
        *(float4*)&kr[r][c*4] = *(const float4*)&K[(rowbase + r)*NKD + c*4];
    }
    __syncthreads();
    int a = tid;
    float acc0 = bias[a], acc1 = bias[a], acc2 = bias[a], acc3 = bias[a];
    #pragma unroll 4
    for (int k = 0; k < NKD; k++) {
        float wv = W[k*NA + a];
        acc0 = fmaf(kr[0][k], wv, acc0);
        acc1 = fmaf(kr[1][k], wv, acc1);
        acc2 = fmaf(kr[2][k], wv, acc2);
        acc3 = fmaf(kr[3][k], wv, acc3);
    }
    P[(rowbase+0)*NA + a] = acc0 * SC2LOG2E;
    P[(rowbase+1)*NA + a] = acc1 * SC2LOG2E;
    P[(rowbase+2)*NA + a] = acc2 * SC2LOG2E;
    P[(rowbase+3)*NA + a] = acc3 * SC2LOG2E;
}

// ---------------- score ----------------
// score[b,i,j] = swsbs + sum_a ws2[a] / (1 + 2^(p1'[b,i,a]+p2'[b,j,a])), masked.
// prep folded in: wst = -2*ws in LDS, swsbs reduced in-block.
// Also writes the masked TRANSPOSED score into the w1 output region (pre-softmax),
// via an LDS tile so both global writes are coalesced. softmax then runs in-place on w1.
#define P1_STRIDE 132
#define P2_STRIDE 36

#define TERM(acc, wv, xv, yv) acc = fmaf((wv), RCPF(1.0f + EXP2F((xv)+(yv))), (acc))

__global__ __launch_bounds__(256) void score_kernel(
    const float* __restrict__ p1, const float* __restrict__ p2,
    const float* __restrict__ ws, const float* __restrict__ bs,
    const int* __restrict__ len1, const int* __restrict__ len2,
    float* __restrict__ score, float* __restrict__ w1pre)
{
    __shared__ float p1t[32][P1_STRIDE];
    __shared__ float p2t[NA][P2_STRIDE];
    __shared__ float wst[NA];
    __shared__ float wsum[2];
    __shared__ float tile[32][33];
    int b  = blockIdx.z;
    int i0 = blockIdx.y * 32, j0 = blockIdx.x * 32;
    int tid = threadIdx.x;
    // prep fold: wst = -2*ws, wsum = partial sums of ws
    if (tid < 128) {
        float w = ws[tid];
        wst[tid] = -2.0f * w;
        float v = w;
        #pragma unroll
        for (int o = 32; o > 0; o >>= 1) v += __shfl_xor(v, o);
        if ((tid & 63) == 0) wsum[tid >> 6] = v;
    }
    const float* p1src = p1 + (b*NL1 + i0)*NA;
    const float* p2src = p2 + (b*NL2 + j0)*NA;
    // stage p1: 32 rows x 32 float4
    for (int idx = tid; idx < 1024; idx += 256) {
        int r = idx >> 5, c = idx & 31;
        *(float4*)&p1t[r][c*4] = *(const float4*)&p1src[r*NA + c*4];
    }
    // stage p2 transposed: read float4 (j, 4a), scatter to p2t[a][j]
    for (int idx = tid; idx < 1024; idx += 256) {
        int j = idx >> 5, c = idx & 31;
        float4 t = *(const float4*)&p2src[j*NA + c*4];
        p2t[c*4+0][j] = t.x; p2t[c*4+1][j] = t.y;
        p2t[c*4+2][j] = t.z; p2t[c*4+3][j] = t.w;
    }
    __syncthreads();

    int tx = tid & 15, ty = tid >> 4;
    int il = ty*2, jl = tx*2;
    float acc00 = 0.f, acc01 = 0.f, acc10 = 0.f, acc11 = 0.f;
    #pragma unroll 4
    for (int a = 0; a < NA; a += 2) {
        float2 wv = *(float2*)&wst[a];
        float2 x0 = *(float2*)&p1t[il  ][a];
        float2 x1 = *(float2*)&p1t[il+1][a];
        float2 y0 = *(float2*)&p2t[a  ][jl];
        float2 y1 = *(float2*)&p2t[a+1][jl];
        TERM(acc00, wv.x, x0.x, y0.x); TERM(acc00, wv.y, x0.y, y1.x);
        TERM(acc01, wv.x, x0.x, y0.y); TERM(acc01, wv.y, x0.y, y1.y);
        TERM(acc10, wv.x, x1.x, y0.x); TERM(acc10, wv.y, x1.y, y1.x);
        TERM(acc11, wv.x, x1.x, y0.y); TERM(acc11, wv.y, x1.y, y1.y);
    }
    float sb = wsum[0] + wsum[1] + bs[0];
    int n1 = len1[b], n2 = len2[b];
    float accs[2][2] = {{acc00, acc01}, {acc10, acc11}};
    #pragma unroll
    for (int di = 0; di < 2; di++) {
        #pragma unroll
        for (int dj = 0; dj < 2; dj++) {
            int gi = i0 + il + di, gj = j0 + jl + dj;
            float v = accs[di][dj] + sb;
            int rp = (gi >= n1), cp = (gj >= n2);
            if (rp + cp == 1) v = MASK_NEG;
            score[(b*NL1 + gi)*NL2 + gj] = v;
            tile[il + di][jl + dj] = v;   // local [i][j]
        }
    }
    __syncthreads();
    // transposed coalesced write: w1pre[b, j, i] = tile[i][j]
    #pragma unroll
    for (int di = 0; di < 2; di++) {
        int rr = il + di;  // local j
        float2 t = make_float2(tile[jl][rr], tile[jl+1][rr]);
        *(float2*)&w1pre[((size_t)b*NL2 + j0 + rr)*NL1 + i0 + jl] = t;
    }
}

// ---------------- merged softmax (row-wise over 512) ----------------
// blocks 0..2047: w2[row] = softmax(score[row]); blocks 2048..4095: w1[row] in-place.
__device__ __forceinline__ float wave_max(float v) {
    #pragma unroll
    for (int o = 32; o > 0; o >>= 1) v = fmaxf(v, __shfl_xor(v, o));
    return v;
}
__device__ __forceinline__ float wave_sum(float v) {
    #pragma unroll
    for (int o = 32; o > 0; o >>= 1) v += __shfl_xor(v, o);
    return v;
}

__global__ __launch_bounds__(256) void softmax_both(const float* __restrict__ score,
                                                    float* __restrict__ w2,
                                                    float* __restrict__ w1)
{
    __shared__ float sm[4], ss[4];
    int row = blockIdx.x, tid = threadIdx.x;
    const float* s; float* d;
    if (row < NB*NL1) { s = score + (size_t)row * NL2; d = w2 + (size_t)row * NL2; }
    else { size_t r = row - NB*NL1; s = w1 + r * NL1; d = w1 + r * NL1; }
    float x0 = s[tid], x1 = s[tid + 256];
    float m = wave_max(fmaxf(x0, x1));
    if ((tid & 63) == 0) sm[tid >> 6] = m;
    __syncthreads();
    m = fmaxf(fmaxf(sm[0], sm[1]), fmaxf(sm[2], sm[3]));
    float e0 = __expf(x0 - m), e1 = __expf(x1 - m);
    float sum = wave_sum(e0 + e1);
    if ((tid & 63) == 0) ss[tid >> 6] = sum;
    __syncthreads();
    sum = (ss[0] + ss[1]) + (ss[2] + ss[3]);
    float inv = 1.0f / sum;
    d[tid] = e0 * inv; d[tid + 256] = e1 * inv;
}

// ---------------- output matmuls (LDS-free, scalar-W / vector-V) ----------------
// The LDS pipe (~85 B/cy/CU for ds_read_b128) was the invariant wall (~31 us) across
// all staged variants. This version uses NO LDS:
//  - wave w owns 8 output rows (r0+8w..+8); lane owns 1 column (d0+lane).
//  - W[row][s] is wave-uniform (readfirstlane on wave id) -> scalar/SMEM loads,
//    zero LDS + zero VALU cost for the broadcast operand.
//  - V[s][d0+lane] is a coalesced 256B vector load; the 512x64 panel streams
//    through L1 (32 KB) shared by all 8 waves.
//  - No barriers, no staging: waves free-run; 2 waves/SIMD cover load latency.
// FMA-issue floor: 4096 FMA/thread * 2cy * 2 waves/SIMD = 16.4K cy = 6.8 us.
__global__ __launch_bounds__(512) void out_matmul(
    const float* __restrict__ w2m, const float* __restrict__ w1m,
    const float* __restrict__ v2,  const float* __restrict__ v1,
    float* __restrict__ o2, float* __restrict__ o1)
{
    int z = blockIdx.z; int b = z >> 1, m = z & 1;
    const float* Wm = (m ? w1m : w2m) + (size_t)b * NL1 * NL2;
    const float* Vm = (m ? v1 : v2)   + (size_t)b * NL2 * NV;
    float*       Om = (m ? o1 : o2)   + (size_t)b * NL1 * NV;
    int r0 = blockIdx.y * 64, d0 = blockIdx.x * 64;
    int tid  = threadIdx.x;
    int wid  = __builtin_amdgcn_readfirstlane(tid >> 6);   // wave id 0..7, provably uniform
    int lane = tid & 63;
    const float* Wrow = Wm + (size_t)(r0 + wid * 8) * 512; // uniform base
    const float* Vcol = Vm + d0 + lane;

    float acc[8] = {};
    #pragma unroll 2
    for (int s = 0; s < 512; s += 4) {
        float4 w[8];
        #pragma unroll
        for (int k = 0; k < 8; k++)
            w[k] = *(const float4*)&Wrow[(size_t)k * 512 + s];
        float va = Vcol[(size_t)(s+0) * NV];
        float vb = Vcol[(size_t)(s+1) * NV];
        float vc = Vcol[(size_t)(s+2) * NV];
        float vd = Vcol[(size_t)(s+3) * NV];
        #pragma unroll
        for (int k = 0; k < 8; k++) {
            acc[k] = fmaf(w[k].x, va, acc[k]);
            acc[k] = fmaf(w[k].y, vb, acc[k]);
            acc[k] = fmaf(w[k].z, vc, acc[k]);
            acc[k] = fmaf(w[k].w, vd, acc[k]);
        }
    }
    #pragma unroll
    for (int k = 0; k < 8; k++)
        Om[(size_t)(r0 + wid * 8 + k) * NV + d0 + lane] = acc[k];
}

extern "C" void kernel_launch(void* const* d_in, const int* in_sizes, int n_in,
                              void* d_out, int out_size, void* d_ws, size_t ws_size,
                              hipStream_t stream) {
    const float* k1  = (const float*)d_in[0];
    const float* k2  = (const float*)d_in[1];
    const float* v1  = (const float*)d_in[2];
    const float* v2  = (const float*)d_in[3];
    const float* W1  = (const float*)d_in[4];
    const float* b1  = (const float*)d_in[5];
    const float* W2  = (const float*)d_in[6];
    const float* b2  = (const float*)d_in[7];
    const float* wsv = (const float*)d_in[8];
    const float* bsp = (const float*)d_in[9];
    const int* len1  = (const int*)d_in[10];
    const int* len2  = (const int*)d_in[11];

    float* out   = (float*)d_out;
    float* o1    = out + O1_OFF;
    float* o2    = out + O2_OFF;
    float* w1    = out + W1_OFF;
    float* w2    = out + W2_OFF;
    float* score = out + SC_OFF;

    float* p1    = (float*)d_ws;           // B*L1*A floats (pre-scaled)
    float* p2    = p1 + NB*NL1*NA;         // B*L2*A floats (pre-scaled)

    proj_kernel<<<dim3((NB*NL1)/4 + (NB*NL2)/4), 128, 0, stream>>>(k1, k2, W1, b1, W2, b2, p1, p2);
    score_kernel<<<dim3(NL2/32, NL1/32, NB), 256, 0, stream>>>(p1, p2, wsv, bsp, len1, len2, score, w1);
    softmax_both<<<dim3(NB*NL1 + NB*NL2), 256, 0, stream>>>(score, w2, w1);
    out_matmul<<<dim3(NV/64, NL1/64, NB*2), 512, 0, stream>>>(w2, w1, v2, v1, o2, o1);
}

// Round 6
// 76.951 us; speedup vs baseline: 1.3214x; 1.3214x over previous
//
#include <hip/hip_runtime.h>
#include <math.h>

#define NB 4
#define NL1 512
#define NL2 512
#define NKD 256
#define NA 128
#define NV 256

// output layout (floats): o1 [B,L2,V], o2 [B,L1,V], w1 [B,L2,L1], w2 [B,L1,L2], score [B,L1,L2]
#define O1_OFF 0
#define O2_OFF (NB*NL2*NV)                 // 524288
#define W1_OFF (O2_OFF + NB*NL1*NV)        // 1048576
#define W2_OFF (W1_OFF + NB*NL2*NL1)       // 2097152
#define SC_OFF (W2_OFF + NB*NL1*NL2)       // 3145728

// masked score positions use -1e30f, NOT -inf (harness absmax: (-inf)-(-inf)=nan fails).
#define MASK_NEG (-1e30f)

// p1/p2 are pre-scaled by 2*log2(e) so e^{2z} = 2^{p1'+p2'}
#define SC2LOG2E 2.8853900817779268f

#if __has_builtin(__builtin_amdgcn_exp2f)
#define EXP2F(x) __builtin_amdgcn_exp2f(x)
#else
#define EXP2F(x) __expf((x) * 0.6931471805599453f)
#endif
#if __has_builtin(__builtin_amdgcn_rcpf)
#define RCPF(x) __builtin_amdgcn_rcpf(x)
#else
#define RCPF(x) (1.0f / (x))
#endif

// ---------------- projection: p = SC2LOG2E * (K @ W + b) ----------------
__global__ __launch_bounds__(128) void proj_kernel(
    const float* __restrict__ k1, const float* __restrict__ k2,
    const float* __restrict__ W1, const float* __restrict__ b1,
    const float* __restrict__ W2, const float* __restrict__ b2,
    float* __restrict__ p1, float* __restrict__ p2)
{
    __shared__ float kr[4][NKD];
    int blk = blockIdx.x;
    int tid = threadIdx.x;
    const float *K, *W, *bias; float* P; int rowbase;
    if (blk < (NB*NL1)/4) { K = k1; W = W1; bias = b1; P = p1; rowbase = blk*4; }
    else                  { K = k2; W = W2; bias = b2; P = p2; rowbase = (blk - (NB*NL1)/4)*4; }
    for (int idx = tid; idx < 256; idx += 128) {
        int r = idx >> 6, c = idx & 63;
        *(float4*)&kr[r][c*4] = *(const float4*)&K[(rowbase + r)*NKD + c*4];
    }
    __syncthreads();
    int a = tid;
    float acc0 = bias[a], acc1 = bias[a], acc2 = bias[a], acc3 = bias[a];
    #pragma unroll 4
    for (int k = 0; k < NKD; k++) {
        float wv = W[k*NA + a];
        acc0 = fmaf(kr[0][k], wv, acc0);
        acc1 = fmaf(kr[1][k], wv, acc1);
        acc2 = fmaf(kr[2][k], wv, acc2);
        acc3 = fmaf(kr[3][k], wv, acc3);
    }
    P[(rowbase+0)*NA + a] = acc0 * SC2LOG2E;
    P[(rowbase+1)*NA + a] = acc1 * SC2LOG2E;
    P[(rowbase+2)*NA + a] = acc2 * SC2LOG2E;
    P[(rowbase+3)*NA + a] = acc3 * SC2LOG2E;
}

// ---------------- score ----------------
#define P1_STRIDE 132
#define P2_STRIDE 36

#define TERM(acc, wv, xv, yv) acc = fmaf((wv), RCPF(1.0f + EXP2F((xv)+(yv))), (acc))

__global__ __launch_bounds__(256) void score_kernel(
    const float* __restrict__ p1, const float* __restrict__ p2,
    const float* __restrict__ ws, const float* __restrict__ bs,
    const int* __restrict__ len1, const int* __restrict__ len2,
    float* __restrict__ score, float* __restrict__ w1pre)
{
    __shared__ float p1t[32][P1_STRIDE];
    __shared__ float p2t[NA][P2_STRIDE];
    __shared__ float wst[NA];
    __shared__ float wsum[2];
    __shared__ float tile[32][33];
    int b  = blockIdx.z;
    int i0 = blockIdx.y * 32, j0 = blockIdx.x * 32;
    int tid = threadIdx.x;
    if (tid < 128) {
        float w = ws[tid];
        wst[tid] = -2.0f * w;
        float v = w;
        #pragma unroll
        for (int o = 32; o > 0; o >>= 1) v += __shfl_xor(v, o);
        if ((tid & 63) == 0) wsum[tid >> 6] = v;
    }
    const float* p1src = p1 + (b*NL1 + i0)*NA;
    const float* p2src = p2 + (b*NL2 + j0)*NA;
    for (int idx = tid; idx < 1024; idx += 256) {
        int r = idx >> 5, c = idx & 31;
        *(float4*)&p1t[r][c*4] = *(const float4*)&p1src[r*NA + c*4];
    }
    for (int idx = tid; idx < 1024; idx += 256) {
        int j = idx >> 5, c = idx & 31;
        float4 t = *(const float4*)&p2src[j*NA + c*4];
        p2t[c*4+0][j] = t.x; p2t[c*4+1][j] = t.y;
        p2t[c*4+2][j] = t.z; p2t[c*4+3][j] = t.w;
    }
    __syncthreads();

    int tx = tid & 15, ty = tid >> 4;
    int il = ty*2, jl = tx*2;
    float acc00 = 0.f, acc01 = 0.f, acc10 = 0.f, acc11 = 0.f;
    #pragma unroll 4
    for (int a = 0; a < NA; a += 2) {
        float2 wv = *(float2*)&wst[a];
        float2 x0 = *(float2*)&p1t[il  ][a];
        float2 x1 = *(float2*)&p1t[il+1][a];
        float2 y0 = *(float2*)&p2t[a  ][jl];
        float2 y1 = *(float2*)&p2t[a+1][jl];
        TERM(acc00, wv.x, x0.x, y0.x); TERM(acc00, wv.y, x0.y, y1.x);
        TERM(acc01, wv.x, x0.x, y0.y); TERM(acc01, wv.y, x0.y, y1.y);
        TERM(acc10, wv.x, x1.x, y0.x); TERM(acc10, wv.y, x1.y, y1.x);
        TERM(acc11, wv.x, x1.x, y0.y); TERM(acc11, wv.y, x1.y, y1.y);
    }
    float sb = wsum[0] + wsum[1] + bs[0];
    int n1 = len1[b], n2 = len2[b];
    float accs[2][2] = {{acc00, acc01}, {acc10, acc11}};
    #pragma unroll
    for (int di = 0; di < 2; di++) {
        #pragma unroll
        for (int dj = 0; dj < 2; dj++) {
            int gi = i0 + il + di, gj = j0 + jl + dj;
            float v = accs[di][dj] + sb;
            int rp = (gi >= n1), cp = (gj >= n2);
            if (rp + cp == 1) v = MASK_NEG;
            score[(b*NL1 + gi)*NL2 + gj] = v;
            tile[il + di][jl + dj] = v;   // local [i][j]
        }
    }
    __syncthreads();
    #pragma unroll
    for (int di = 0; di < 2; di++) {
        int rr = il + di;  // local j
        float2 t = make_float2(tile[jl][rr], tile[jl+1][rr]);
        *(float2*)&w1pre[((size_t)b*NL2 + j0 + rr)*NL1 + i0 + jl] = t;
    }
}

// ---------------- merged softmax (row-wise over 512) ----------------
__device__ __forceinline__ float wave_max(float v) {
    #pragma unroll
    for (int o = 32; o > 0; o >>= 1) v = fmaxf(v, __shfl_xor(v, o));
    return v;
}
__device__ __forceinline__ float wave_sum(float v) {
    #pragma unroll
    for (int o = 32; o > 0; o >>= 1) v += __shfl_xor(v, o);
    return v;
}

__global__ __launch_bounds__(256) void softmax_both(const float* __restrict__ score,
                                                    float* __restrict__ w2,
                                                    float* __restrict__ w1)
{
    __shared__ float sm[4], ss[4];
    int row = blockIdx.x, tid = threadIdx.x;
    const float* s; float* d;
    if (row < NB*NL1) { s = score + (size_t)row * NL2; d = w2 + (size_t)row * NL2; }
    else { size_t r = row - NB*NL1; s = w1 + r * NL1; d = w1 + r * NL1; }
    float x0 = s[tid], x1 = s[tid + 256];
    float m = wave_max(fmaxf(x0, x1));
    if ((tid & 63) == 0) sm[tid >> 6] = m;
    __syncthreads();
    m = fmaxf(fmaxf(sm[0], sm[1]), fmaxf(sm[2], sm[3]));
    float e0 = __expf(x0 - m), e1 = __expf(x1 - m);
    float sum = wave_sum(e0 + e1);
    if ((tid & 63) == 0) ss[tid >> 6] = sum;
    __syncthreads();
    sum = (ss[0] + ss[1]) + (ss[2] + ss[3]);
    float inv = 1.0f / sum;
    d[tid] = e0 * inv; d[tid + 256] = e1 * inv;
}

// ---------------- output matmuls (bf16 MFMA) ----------------
// All fp32 data-path variants pinned at 32-50 us (LDS pipe / cache-latency walls).
// This uses the matrix pipe: mfma_f32_16x16x32_bf16, fp32 accumulate.
//  - 64x64 tile, 256 thr = 4 waves (2x2); wave = 2x2 MFMA tiles, K-loop 16 steps of 32.
//  - V staged ONCE transposed+bf16 in LDS (Vt[d][s], stride 520) -> B-frag is one
//    contiguous ds_read_b128. No per-step barriers: waves free-run after one sync.
//  - W read per-lane from global (fp32, L2-resident: softmax just wrote it), cvt->bf16
//    in-register (RNE). Frag layout (m89/H1): A row=l&15 k=8*(l>>4)+e; B col=l&15 same;
//    C/D col=l&15 row=4*(l>>4)+reg.
typedef __attribute__((ext_vector_type(8))) short bf16x8;
typedef __attribute__((ext_vector_type(4))) float f32x4;

__device__ __forceinline__ unsigned short f2bf(float f) {
    unsigned u = __float_as_uint(f);
    u += 0x7fffu + ((u >> 16) & 1u);          // round-to-nearest-even
    return (unsigned short)(u >> 16);
}

#define VT_STRIDE 520   // 512 + 8 pad (bf16 elems); 1040 B row, 16B-aligned

__global__ __launch_bounds__(256) void out_matmul(
    const float* __restrict__ w2m, const float* __restrict__ w1m,
    const float* __restrict__ v2,  const float* __restrict__ v1,
    float* __restrict__ o2, float* __restrict__ o1)
{
    __shared__ unsigned short Vt[64 * VT_STRIDE];
    int z = blockIdx.z; int b = z >> 1, m = z & 1;
    const float* Wm = (m ? w1m : w2m) + (size_t)b * NL1 * NL2;
    const float* Vm = (m ? v1 : v2)   + (size_t)b * NL2 * NV;
    float*       Om = (m ? o1 : o2)   + (size_t)b * NL1 * NV;
    int r0 = blockIdx.y * 64, d0 = blockIdx.x * 64;
    int tid = threadIdx.x;
    int lane = tid & 63, wid = tid >> 6;
    int wy = wid >> 1, wx = wid & 1;
    int lm = lane & 15, kg = lane >> 4;

    // one-time stage: Vt[d][s] = bf16(V[s][d0+d]), s-pairs packed per 32-bit word
    {
        int tm = tid & 15, tg = tid >> 4;      // tg in 0..15
        #pragma unroll 4
        for (int u = 0; u < 16; u++) {
            int s = 2 * tg + 32 * u;
            #pragma unroll
            for (int j = 0; j < 4; j++) {
                int d = tm + 16 * j;
                float f0 = Vm[(size_t)s * NV + d0 + d];
                float f1 = Vm[(size_t)(s + 1) * NV + d0 + d];
                unsigned pk = (unsigned)f2bf(f0) | ((unsigned)f2bf(f1) << 16);
                *(unsigned*)&Vt[d * VT_STRIDE + s] = pk;
            }
        }
    }
    __syncthreads();

    const float* Wlo = Wm + (size_t)(r0 + wy * 32 + lm) * 512;
    const float* Whi = Wlo + (size_t)16 * 512;
    const unsigned short* Vlo = &Vt[(wx * 32 + lm) * VT_STRIDE];
    const unsigned short* Vhi = Vlo + 16 * VT_STRIDE;

    f32x4 acc00 = {0.f,0.f,0.f,0.f}, acc01 = {0.f,0.f,0.f,0.f};
    f32x4 acc10 = {0.f,0.f,0.f,0.f}, acc11 = {0.f,0.f,0.f,0.f};
    #pragma unroll 4
    for (int t = 0; t < 16; t++) {
        int s0 = t * 32 + 8 * kg;
        float4 a0l = *(const float4*)(Wlo + s0);
        float4 a0h = *(const float4*)(Wlo + s0 + 4);
        float4 a1l = *(const float4*)(Whi + s0);
        float4 a1h = *(const float4*)(Whi + s0 + 4);
        bf16x8 fa0, fa1;
        fa0[0] = (short)f2bf(a0l.x); fa0[1] = (short)f2bf(a0l.y);
        fa0[2] = (short)f2bf(a0l.z); fa0[3] = (short)f2bf(a0l.w);
        fa0[4] = (short)f2bf(a0h.x); fa0[5] = (short)f2bf(a0h.y);
        fa0[6] = (short)f2bf(a0h.z); fa0[7] = (short)f2bf(a0h.w);
        fa1[0] = (short)f2bf(a1l.x); fa1[1] = (short)f2bf(a1l.y);
        fa1[2] = (short)f2bf(a1l.z); fa1[3] = (short)f2bf(a1l.w);
        fa1[4] = (short)f2bf(a1h.x); fa1[5] = (short)f2bf(a1h.y);
        fa1[6] = (short)f2bf(a1h.z); fa1[7] = (short)f2bf(a1h.w);
        bf16x8 fb0 = *(const bf16x8*)(Vlo + s0);
        bf16x8 fb1 = *(const bf16x8*)(Vhi + s0);
        acc00 = __builtin_amdgcn_mfma_f32_16x16x32_bf16(fa0, fb0, acc00, 0, 0, 0);
        acc01 = __builtin_amdgcn_mfma_f32_16x16x32_bf16(fa0, fb1, acc01, 0, 0, 0);
        acc10 = __builtin_amdgcn_mfma_f32_16x16x32_bf16(fa1, fb0, acc10, 0, 0, 0);
        acc11 = __builtin_amdgcn_mfma_f32_16x16x32_bf16(fa1, fb1, acc11, 0, 0, 0);
    }

    int rlo = r0 + wy * 32 + 4 * kg;
    int clo = d0 + wx * 32 + lm;
    #pragma unroll
    for (int e = 0; e < 4; e++) {
        Om[(size_t)(rlo + e) * NV + clo]           = acc00[e];
        Om[(size_t)(rlo + e) * NV + clo + 16]      = acc01[e];
        Om[(size_t)(rlo + 16 + e) * NV + clo]      = acc10[e];
        Om[(size_t)(rlo + 16 + e) * NV + clo + 16] = acc11[e];
    }
}

extern "C" void kernel_launch(void* const* d_in, const int* in_sizes, int n_in,
                              void* d_out, int out_size, void* d_ws, size_t ws_size,
                              hipStream_t stream) {
    const float* k1  = (const float*)d_in[0];
    const float* k2  = (const float*)d_in[1];
    const float* v1  = (const float*)d_in[2];
    const float* v2  = (const float*)d_in[3];
    const float* W1  = (const float*)d_in[4];
    const float* b1  = (const float*)d_in[5];
    const float* W2  = (const float*)d_in[6];
    const float* b2  = (const float*)d_in[7];
    const float* wsv = (const float*)d_in[8];
    const float* bsp = (const float*)d_in[9];
    const int* len1  = (const int*)d_in[10];
    const int* len2  = (const int*)d_in[11];

    float* out   = (float*)d_out;
    float* o1    = out + O1_OFF;
    float* o2    = out + O2_OFF;
    float* w1    = out + W1_OFF;
    float* w2    = out + W2_OFF;
    float* score = out + SC_OFF;

    float* p1    = (float*)d_ws;           // B*L1*A floats (pre-scaled)
    float* p2    = p1 + NB*NL1*NA;         // B*L2*A floats (pre-scaled)

    proj_kernel<<<dim3((NB*NL1)/4 + (NB*NL2)/4), 128, 0, stream>>>(k1, k2, W1, b1, W2, b2, p1, p2);
    score_kernel<<<dim3(NL2/32, NL1/32, NB), 256, 0, stream>>>(p1, p2, wsv, bsp, len1, len2, score, w1);
    softmax_both<<<dim3(NB*NL1 + NB*NL2), 256, 0, stream>>>(score, w2, w1);
    out_matmul<<<dim3(NV/64, NL1/64, NB*2), 256, 0, stream>>>(w2, w1, v2, v1, o2, o1);
}

// Round 7
// 72.674 us; speedup vs baseline: 1.3992x; 1.0589x over previous
//
#include <hip/hip_runtime.h>
#include <math.h>

#define NB 4
#define NL1 512
#define NL2 512
#define NKD 256
#define NA 128
#define NV 256

// output layout (floats): o1 [B,L2,V], o2 [B,L1,V], w1 [B,L2,L1], w2 [B,L1,L2], score [B,L1,L2]
#define O1_OFF 0
#define O2_OFF (NB*NL2*NV)                 // 524288
#define W1_OFF (O2_OFF + NB*NL1*NV)        // 1048576
#define W2_OFF (W1_OFF + NB*NL2*NL1)       // 2097152
#define SC_OFF (W2_OFF + NB*NL1*NL2)       // 3145728

// masked score positions use -1e30f, NOT -inf (harness absmax: (-inf)-(-inf)=nan fails).
#define MASK_NEG (-1e30f)

// p1/p2 are pre-scaled by 2*log2(e) so e^{2z} = 2^{p1'+p2'}
#define SC2LOG2E 2.8853900817779268f

#if __has_builtin(__builtin_amdgcn_exp2f)
#define EXP2F(x) __builtin_amdgcn_exp2f(x)
#else
#define EXP2F(x) __expf((x) * 0.6931471805599453f)
#endif
#if __has_builtin(__builtin_amdgcn_rcpf)
#define RCPF(x) __builtin_amdgcn_rcpf(x)
#else
#define RCPF(x) (1.0f / (x))
#endif

// ---------------- projection: p = SC2LOG2E * (K @ W + b) ----------------
__global__ __launch_bounds__(128) void proj_kernel(
    const float* __restrict__ k1, const float* __restrict__ k2,
    const float* __restrict__ W1, const float* __restrict__ b1,
    const float* __restrict__ W2, const float* __restrict__ b2,
    float* __restrict__ p1, float* __restrict__ p2)
{
    __shared__ float kr[4][NKD];
    int blk = blockIdx.x;
    int tid = threadIdx.x;
    const float *K, *W, *bias; float* P; int rowbase;
    if (blk < (NB*NL1)/4) { K = k1; W = W1; bias = b1; P = p1; rowbase = blk*4; }
    else                  { K = k2; W = W2; bias = b2; P = p2; rowbase = (blk - (NB*NL1)/4)*4; }
    for (int idx = tid; idx < 256; idx += 128) {
        int r = idx >> 6, c = idx & 63;
        *(float4*)&kr[r][c*4] = *(const float4*)&K[(rowbase + r)*NKD + c*4];
    }
    __syncthreads();
    int a = tid;
    float acc0 = bias[a], acc1 = bias[a], acc2 = bias[a], acc3 = bias[a];
    #pragma unroll 4
    for (int k = 0; k < NKD; k++) {
        float wv = W[k*NA + a];
        acc0 = fmaf(kr[0][k], wv, acc0);
        acc1 = fmaf(kr[1][k], wv, acc1);
        acc2 = fmaf(kr[2][k], wv, acc2);
        acc3 = fmaf(kr[3][k], wv, acc3);
    }
    P[(rowbase+0)*NA + a] = acc0 * SC2LOG2E;
    P[(rowbase+1)*NA + a] = acc1 * SC2LOG2E;
    P[(rowbase+2)*NA + a] = acc2 * SC2LOG2E;
    P[(rowbase+3)*NA + a] = acc3 * SC2LOG2E;
}

// ---------------- score ----------------
#define P1_STRIDE 132
#define P2_STRIDE 36

#define TERM(acc, wv, xv, yv) acc = fmaf((wv), RCPF(1.0f + EXP2F((xv)+(yv))), (acc))

__global__ __launch_bounds__(256) void score_kernel(
    const float* __restrict__ p1, const float* __restrict__ p2,
    const float* __restrict__ ws, const float* __restrict__ bs,
    const int* __restrict__ len1, const int* __restrict__ len2,
    float* __restrict__ score, float* __restrict__ w1pre)
{
    __shared__ float p1t[32][P1_STRIDE];
    __shared__ float p2t[NA][P2_STRIDE];
    __shared__ float wst[NA];
    __shared__ float wsum[2];
    __shared__ float tile[32][33];
    int b  = blockIdx.z;
    int i0 = blockIdx.y * 32, j0 = blockIdx.x * 32;
    int tid = threadIdx.x;
    if (tid < 128) {
        float w = ws[tid];
        wst[tid] = -2.0f * w;
        float v = w;
        #pragma unroll
        for (int o = 32; o > 0; o >>= 1) v += __shfl_xor(v, o);
        if ((tid & 63) == 0) wsum[tid >> 6] = v;
    }
    const float* p1src = p1 + (b*NL1 + i0)*NA;
    const float* p2src = p2 + (b*NL2 + j0)*NA;
    for (int idx = tid; idx < 1024; idx += 256) {
        int r = idx >> 5, c = idx & 31;
        *(float4*)&p1t[r][c*4] = *(const float4*)&p1src[r*NA + c*4];
    }
    for (int idx = tid; idx < 1024; idx += 256) {
        int j = idx >> 5, c = idx & 31;
        float4 t = *(const float4*)&p2src[j*NA + c*4];
        p2t[c*4+0][j] = t.x; p2t[c*4+1][j] = t.y;
        p2t[c*4+2][j] = t.z; p2t[c*4+3][j] = t.w;
    }
    __syncthreads();

    int tx = tid & 15, ty = tid >> 4;
    int il = ty*2, jl = tx*2;
    float acc00 = 0.f, acc01 = 0.f, acc10 = 0.f, acc11 = 0.f;
    #pragma unroll 4
    for (int a = 0; a < NA; a += 2) {
        float2 wv = *(float2*)&wst[a];
        float2 x0 = *(float2*)&p1t[il  ][a];
        float2 x1 = *(float2*)&p1t[il+1][a];
        float2 y0 = *(float2*)&p2t[a  ][jl];
        float2 y1 = *(float2*)&p2t[a+1][jl];
        TERM(acc00, wv.x, x0.x, y0.x); TERM(acc00, wv.y, x0.y, y1.x);
        TERM(acc01, wv.x, x0.x, y0.y); TERM(acc01, wv.y, x0.y, y1.y);
        TERM(acc10, wv.x, x1.x, y0.x); TERM(acc10, wv.y, x1.y, y1.x);
        TERM(acc11, wv.x, x1.x, y0.y); TERM(acc11, wv.y, x1.y, y1.y);
    }
    float sb = wsum[0] + wsum[1] + bs[0];
    int n1 = len1[b], n2 = len2[b];
    float accs[2][2] = {{acc00, acc01}, {acc10, acc11}};
    #pragma unroll
    for (int di = 0; di < 2; di++) {
        #pragma unroll
        for (int dj = 0; dj < 2; dj++) {
            int gi = i0 + il + di, gj = j0 + jl + dj;
            float v = accs[di][dj] + sb;
            int rp = (gi >= n1), cp = (gj >= n2);
            if (rp + cp == 1) v = MASK_NEG;
            score[(b*NL1 + gi)*NL2 + gj] = v;
            tile[il + di][jl + dj] = v;   // local [i][j]
        }
    }
    __syncthreads();
    #pragma unroll
    for (int di = 0; di < 2; di++) {
        int rr = il + di;  // local j
        float2 t = make_float2(tile[jl][rr], tile[jl+1][rr]);
        *(float2*)&w1pre[((size_t)b*NL2 + j0 + rr)*NL1 + i0 + jl] = t;
    }
}

// ---------------- merged softmax (row-wise over 512) ----------------
__device__ __forceinline__ float wave_max(float v) {
    #pragma unroll
    for (int o = 32; o > 0; o >>= 1) v = fmaxf(v, __shfl_xor(v, o));
    return v;
}
__device__ __forceinline__ float wave_sum(float v) {
    #pragma unroll
    for (int o = 32; o > 0; o >>= 1) v += __shfl_xor(v, o);
    return v;
}

__global__ __launch_bounds__(256) void softmax_both(const float* __restrict__ score,
                                                    float* __restrict__ w2,
                                                    float* __restrict__ w1)
{
    __shared__ float sm[4], ss[4];
    int row = blockIdx.x, tid = threadIdx.x;
    const float* s; float* d;
    if (row < NB*NL1) { s = score + (size_t)row * NL2; d = w2 + (size_t)row * NL2; }
    else { size_t r = row - NB*NL1; s = w1 + r * NL1; d = w1 + r * NL1; }
    float x0 = s[tid], x1 = s[tid + 256];
    float m = wave_max(fmaxf(x0, x1));
    if ((tid & 63) == 0) sm[tid >> 6] = m;
    __syncthreads();
    m = fmaxf(fmaxf(sm[0], sm[1]), fmaxf(sm[2], sm[3]));
    float e0 = __expf(x0 - m), e1 = __expf(x1 - m);
    float sum = wave_sum(e0 + e1);
    if ((tid & 63) == 0) ss[tid >> 6] = sum;
    __syncthreads();
    sum = (ss[0] + ss[1]) + (ss[2] + ss[3]);
    float inv = 1.0f / sum;
    d[tid] = e0 * inv; d[tid + 256] = e1 * inv;
}

// ---------------- output matmuls (bf16 MFMA, both operands LDS-staged) ----------------
// R6 post-mortem: A-path read W per-lane from global at 2KB row stride -> each
// global_load_dwordx4 touched ~16 cache lines; MFMA starved behind scatter VMEM.
// Fix: stage W full-K into LDS as bf16 with COALESCED loads (lanes span 512B
// contiguous per row), same layout family as Vt. K-loop is then 4 ds_read_b128 +
// 4 MFMA per step, barrier-free. LDS = 2 x 64x520 bf16 = 130 KB (<=160 KB/CU).
// Frag layout (verified passing in R6): A row=l&15, k=8*(l>>4)+e; B col=l&15 same k;
// C/D col=l&15, row=4*(l>>4)+reg.
typedef __attribute__((ext_vector_type(8))) short bf16x8;
typedef __attribute__((ext_vector_type(4))) float f32x4;

__device__ __forceinline__ unsigned short f2bf(float f) {
    unsigned u = __float_as_uint(f);
    u += 0x7fffu + ((u >> 16) & 1u);          // round-to-nearest-even
    return (unsigned short)(u >> 16);
}

#define VT_STRIDE 520   // 512 + 8 pad (bf16 elems); 1040 B row, 16B-aligned

__global__ __launch_bounds__(256) void out_matmul(
    const float* __restrict__ w2m, const float* __restrict__ w1m,
    const float* __restrict__ v2,  const float* __restrict__ v1,
    float* __restrict__ o2, float* __restrict__ o1)
{
    __shared__ unsigned short Wt[64 * VT_STRIDE];
    __shared__ unsigned short Vt[64 * VT_STRIDE];
    int z = blockIdx.z; int b = z >> 1, m = z & 1;
    const float* Wm = (m ? w1m : w2m) + (size_t)b * NL1 * NL2;
    const float* Vm = (m ? v1 : v2)   + (size_t)b * NL2 * NV;
    float*       Om = (m ? o1 : o2)   + (size_t)b * NL1 * NV;
    int r0 = blockIdx.y * 64, d0 = blockIdx.x * 64;
    int tid = threadIdx.x;
    int lane = tid & 63, wid = tid >> 6;
    int wy = wid >> 1, wx = wid & 1;
    int lm = lane & 15, kg = lane >> 4;

    // ---- stage W: coalesced. rows r=(tid>>5)+8p; lanes (tid&31) cover 512B contig.
    {
        int wr = tid >> 5;          // 0..7
        int wc = tid & 31;          // float4 lane within row-half
        #pragma unroll
        for (int p = 0; p < 8; p++) {
            int r = wr + 8 * p;
            const float* src = Wm + (size_t)(r0 + r) * 512;
            unsigned short* dstrow = &Wt[r * VT_STRIDE];
            #pragma unroll
            for (int k = 0; k < 4; k++) {
                int s = 4 * (wc + 32 * k);
                float4 f = *(const float4*)&src[s];
                unsigned lo = (unsigned)f2bf(f.x) | ((unsigned)f2bf(f.y) << 16);
                unsigned hi = (unsigned)f2bf(f.z) | ((unsigned)f2bf(f.w) << 16);
                *(unsigned*)&dstrow[s]     = lo;
                *(unsigned*)&dstrow[s + 2] = hi;
            }
        }
    }
    // ---- stage V transposed: Vt[d][s] = bf16(V[s][d0+d]) (R6 pattern: 2-way writes)
    {
        int tm = tid & 15, tg = tid >> 4;      // tg in 0..15
        #pragma unroll 4
        for (int u = 0; u < 16; u++) {
            int s = 2 * tg + 32 * u;
            #pragma unroll
            for (int j = 0; j < 4; j++) {
                int d = tm + 16 * j;
                float f0 = Vm[(size_t)s * NV + d0 + d];
                float f1 = Vm[(size_t)(s + 1) * NV + d0 + d];
                unsigned pk = (unsigned)f2bf(f0) | ((unsigned)f2bf(f1) << 16);
                *(unsigned*)&Vt[d * VT_STRIDE + s] = pk;
            }
        }
    }
    __syncthreads();

    const unsigned short* Wlo = &Wt[(wy * 32 + lm) * VT_STRIDE];
    const unsigned short* Whi = Wlo + 16 * VT_STRIDE;
    const unsigned short* Vlo = &Vt[(wx * 32 + lm) * VT_STRIDE];
    const unsigned short* Vhi = Vlo + 16 * VT_STRIDE;

    f32x4 acc00 = {0.f,0.f,0.f,0.f}, acc01 = {0.f,0.f,0.f,0.f};
    f32x4 acc10 = {0.f,0.f,0.f,0.f}, acc11 = {0.f,0.f,0.f,0.f};
    #pragma unroll 4
    for (int t = 0; t < 16; t++) {
        int s0 = t * 32 + 8 * kg;
        bf16x8 fa0 = *(const bf16x8*)(Wlo + s0);
        bf16x8 fa1 = *(const bf16x8*)(Whi + s0);
        bf16x8 fb0 = *(const bf16x8*)(Vlo + s0);
        bf16x8 fb1 = *(const bf16x8*)(Vhi + s0);
        acc00 = __builtin_amdgcn_mfma_f32_16x16x32_bf16(fa0, fb0, acc00, 0, 0, 0);
        acc01 = __builtin_amdgcn_mfma_f32_16x16x32_bf16(fa0, fb1, acc01, 0, 0, 0);
        acc10 = __builtin_amdgcn_mfma_f32_16x16x32_bf16(fa1, fb0, acc10, 0, 0, 0);
        acc11 = __builtin_amdgcn_mfma_f32_16x16x32_bf16(fa1, fb1, acc11, 0, 0, 0);
    }

    int rlo = r0 + wy * 32 + 4 * kg;
    int clo = d0 + wx * 32 + lm;
    #pragma unroll
    for (int e = 0; e < 4; e++) {
        Om[(size_t)(rlo + e) * NV + clo]           = acc00[e];
        Om[(size_t)(rlo + e) * NV + clo + 16]      = acc01[e];
        Om[(size_t)(rlo + 16 + e) * NV + clo]      = acc10[e];
        Om[(size_t)(rlo + 16 + e) * NV + clo + 16] = acc11[e];
    }
}

extern "C" void kernel_launch(void* const* d_in, const int* in_sizes, int n_in,
                              void* d_out, int out_size, void* d_ws, size_t ws_size,
                              hipStream_t stream) {
    const float* k1  = (const float*)d_in[0];
    const float* k2  = (const float*)d_in[1];
    const float* v1  = (const float*)d_in[2];
    const float* v2  = (const float*)d_in[3];
    const float* W1  = (const float*)d_in[4];
    const float* b1  = (const float*)d_in[5];
    const float* W2  = (const float*)d_in[6];
    const float* b2  = (const float*)d_in[7];
    const float* wsv = (const float*)d_in[8];
    const float* bsp = (const float*)d_in[9];
    const int* len1  = (const int*)d_in[10];
    const int* len2  = (const int*)d_in[11];

    float* out   = (float*)d_out;
    float* o1    = out + O1_OFF;
    float* o2    = out + O2_OFF;
    float* w1    = out + W1_OFF;
    float* w2    = out + W2_OFF;
    float* score = out + SC_OFF;

    float* p1    = (float*)d_ws;           // B*L1*A floats (pre-scaled)
    float* p2    = p1 + NB*NL1*NA;         // B*L2*A floats (pre-scaled)

    proj_kernel<<<dim3((NB*NL1)/4 + (NB*NL2)/4), 128, 0, stream>>>(k1, k2, W1, b1, W2, b2, p1, p2);
    score_kernel<<<dim3(NL2/32, NL1/32, NB), 256, 0, stream>>>(p1, p2, wsv, bsp, len1, len2, score, w1);
    softmax_both<<<dim3(NB*NL1 + NB*NL2), 256, 0, stream>>>(score, w2, w1);
    out_matmul<<<dim3(NV/64, NL1/64, NB*2), 256, 0, stream>>>(w2, w1, v2, v1, o2, o1);
}

// Round 8
// 71.853 us; speedup vs baseline: 1.4151x; 1.0114x over previous
//
#include <hip/hip_runtime.h>
#include <math.h>

#define NB 4
#define NL1 512
#define NL2 512
#define NKD 256
#define NA 128
#define NV 256

// output layout (floats): o1 [B,L2,V], o2 [B,L1,V], w1 [B,L2,L1], w2 [B,L1,L2], score [B,L1,L2]
#define O1_OFF 0
#define O2_OFF (NB*NL2*NV)                 // 524288
#define W1_OFF (O2_OFF + NB*NL1*NV)        // 1048576
#define W2_OFF (W1_OFF + NB*NL2*NL1)       // 2097152
#define SC_OFF (W2_OFF + NB*NL1*NL2)       // 3145728

// masked score positions use -1e30f, NOT -inf (harness absmax: (-inf)-(-inf)=nan fails).
#define MASK_NEG (-1e30f)

// p1/p2 are pre-scaled by 2*log2(e) so e^{2z} = 2^{p1'+p2'}
#define SC2LOG2E 2.8853900817779268f

#if __has_builtin(__builtin_amdgcn_exp2f)
#define EXP2F(x) __builtin_amdgcn_exp2f(x)
#else
#define EXP2F(x) __expf((x) * 0.6931471805599453f)
#endif
#if __has_builtin(__builtin_amdgcn_rcpf)
#define RCPF(x) __builtin_amdgcn_rcpf(x)
#else
#define RCPF(x) (1.0f / (x))
#endif

// ---------------- projection: p = SC2LOG2E * (K @ W + b) ----------------
__global__ __launch_bounds__(128) void proj_kernel(
    const float* __restrict__ k1, const float* __restrict__ k2,
    const float* __restrict__ W1, const float* __restrict__ b1,
    const float* __restrict__ W2, const float* __restrict__ b2,
    float* __restrict__ p1, float* __restrict__ p2)
{
    __shared__ float kr[4][NKD];
    int blk = blockIdx.x;
    int tid = threadIdx.x;
    const float *K, *W, *bias; float* P; int rowbase;
    if (blk < (NB*NL1)/4) { K = k1; W = W1; bias = b1; P = p1; rowbase = blk*4; }
    else                  { K = k2; W = W2; bias = b2; P = p2; rowbase = (blk - (NB*NL1)/4)*4; }
    for (int idx = tid; idx < 256; idx += 128) {
        int r = idx >> 6, c = idx & 63;
        *(float4*)&kr[r][c*4] = *(const float4*)&K[(rowbase + r)*NKD + c*4];
    }
    __syncthreads();
    int a = tid;
    float acc0 = bias[a], acc1 = bias[a], acc2 = bias[a], acc3 = bias[a];
    #pragma unroll 4
    for (int k = 0; k < NKD; k++) {
        float wv = W[k*NA + a];
        acc0 = fmaf(kr[0][k], wv, acc0);
        acc1 = fmaf(kr[1][k], wv, acc1);
        acc2 = fmaf(kr[2][k], wv, acc2);
        acc3 = fmaf(kr[3][k], wv, acc3);
    }
    P[(rowbase+0)*NA + a] = acc0 * SC2LOG2E;
    P[(rowbase+1)*NA + a] = acc1 * SC2LOG2E;
    P[(rowbase+2)*NA + a] = acc2 * SC2LOG2E;
    P[(rowbase+3)*NA + a] = acc3 * SC2LOG2E;
}

// ---------------- score ----------------
#define P1_STRIDE 132
#define P2_STRIDE 36

#define TERM(acc, wv, xv, yv) acc = fmaf((wv), RCPF(1.0f + EXP2F((xv)+(yv))), (acc))

__global__ __launch_bounds__(256) void score_kernel(
    const float* __restrict__ p1, const float* __restrict__ p2,
    const float* __restrict__ ws, const float* __restrict__ bs,
    const int* __restrict__ len1, const int* __restrict__ len2,
    float* __restrict__ score, float* __restrict__ w1pre)
{
    __shared__ float p1t[32][P1_STRIDE];
    __shared__ float p2t[NA][P2_STRIDE];
    __shared__ float wst[NA];
    __shared__ float wsum[2];
    __shared__ float tile[32][33];
    int b  = blockIdx.z;
    int i0 = blockIdx.y * 32, j0 = blockIdx.x * 32;
    int tid = threadIdx.x;
    if (tid < 128) {
        float w = ws[tid];
        wst[tid] = -2.0f * w;
        float v = w;
        #pragma unroll
        for (int o = 32; o > 0; o >>= 1) v += __shfl_xor(v, o);
        if ((tid & 63) == 0) wsum[tid >> 6] = v;
    }
    const float* p1src = p1 + (b*NL1 + i0)*NA;
    const float* p2src = p2 + (b*NL2 + j0)*NA;
    for (int idx = tid; idx < 1024; idx += 256) {
        int r = idx >> 5, c = idx & 31;
        *(float4*)&p1t[r][c*4] = *(const float4*)&p1src[r*NA + c*4];
    }
    for (int idx = tid; idx < 1024; idx += 256) {
        int j = idx >> 5, c = idx & 31;
        float4 t = *(const float4*)&p2src[j*NA + c*4];
        p2t[c*4+0][j] = t.x; p2t[c*4+1][j] = t.y;
        p2t[c*4+2][j] = t.z; p2t[c*4+3][j] = t.w;
    }
    __syncthreads();

    int tx = tid & 15, ty = tid >> 4;
    int il = ty*2, jl = tx*2;
    float acc00 = 0.f, acc01 = 0.f, acc10 = 0.f, acc11 = 0.f;
    #pragma unroll 2
    for (int a = 0; a < NA; a += 4) {
        float4 wv = *(float4*)&wst[a];
        float4 x0 = *(float4*)&p1t[il  ][a];
        float4 x1 = *(float4*)&p1t[il+1][a];
        float2 y0 = *(float2*)&p2t[a  ][jl];
        float2 y1 = *(float2*)&p2t[a+1][jl];
        float2 y2 = *(float2*)&p2t[a+2][jl];
        float2 y3 = *(float2*)&p2t[a+3][jl];
        TERM(acc00, wv.x, x0.x, y0.x); TERM(acc01, wv.x, x0.x, y0.y);
        TERM(acc10, wv.x, x1.x, y0.x); TERM(acc11, wv.x, x1.x, y0.y);
        TERM(acc00, wv.y, x0.y, y1.x); TERM(acc01, wv.y, x0.y, y1.y);
        TERM(acc10, wv.y, x1.y, y1.x); TERM(acc11, wv.y, x1.y, y1.y);
        TERM(acc00, wv.z, x0.z, y2.x); TERM(acc01, wv.z, x0.z, y2.y);
        TERM(acc10, wv.z, x1.z, y2.x); TERM(acc11, wv.z, x1.z, y2.y);
        TERM(acc00, wv.w, x0.w, y3.x); TERM(acc01, wv.w, x0.w, y3.y);
        TERM(acc10, wv.w, x1.w, y3.x); TERM(acc11, wv.w, x1.w, y3.y);
    }
    float sb = wsum[0] + wsum[1] + bs[0];
    int n1 = len1[b], n2 = len2[b];
    float accs[2][2] = {{acc00, acc01}, {acc10, acc11}};
    #pragma unroll
    for (int di = 0; di < 2; di++) {
        #pragma unroll
        for (int dj = 0; dj < 2; dj++) {
            int gi = i0 + il + di, gj = j0 + jl + dj;
            float v = accs[di][dj] + sb;
            int rp = (gi >= n1), cp = (gj >= n2);
            if (rp + cp == 1) v = MASK_NEG;
            score[(b*NL1 + gi)*NL2 + gj] = v;
            tile[il + di][jl + dj] = v;   // local [i][j]
        }
    }
    __syncthreads();
    #pragma unroll
    for (int di = 0; di < 2; di++) {
        int rr = il + di;  // local j
        float2 t = make_float2(tile[jl][rr], tile[jl+1][rr]);
        *(float2*)&w1pre[((size_t)b*NL2 + j0 + rr)*NL1 + i0 + jl] = t;
    }
}

// ---------------- merged softmax: one WAVE per row, no LDS, no barriers ----------------
// waves 0..2047: w2[row] = softmax(score[row]); 2048..4095: w1[row] in-place.
// lane holds 8 elements (2 float4, fully coalesced); 6-step shuffle reductions.
__global__ __launch_bounds__(256) void softmax_both(const float* __restrict__ score,
                                                    float* __restrict__ w2,
                                                    float* __restrict__ w1)
{
    int row = blockIdx.x * 4 + (threadIdx.x >> 6);
    int lane = threadIdx.x & 63;
    const float* s; float* d;
    if (row < NB*NL1) { s = score + (size_t)row * NL2; d = w2 + (size_t)row * NL2; }
    else { size_t r = row - NB*NL1; s = w1 + r * NL1; d = w1 + r * NL1; }
    float4 v0 = *(const float4*)&s[lane * 4];
    float4 v1 = *(const float4*)&s[256 + lane * 4];
    float m = fmaxf(fmaxf(fmaxf(v0.x, v0.y), fmaxf(v0.z, v0.w)),
                    fmaxf(fmaxf(v1.x, v1.y), fmaxf(v1.z, v1.w)));
    #pragma unroll
    for (int o = 32; o > 0; o >>= 1) m = fmaxf(m, __shfl_xor(m, o));
    float4 e0, e1;
    e0.x = __expf(v0.x - m); e0.y = __expf(v0.y - m);
    e0.z = __expf(v0.z - m); e0.w = __expf(v0.w - m);
    e1.x = __expf(v1.x - m); e1.y = __expf(v1.y - m);
    e1.z = __expf(v1.z - m); e1.w = __expf(v1.w - m);
    float sum = (e0.x + e0.y) + (e0.z + e0.w) + (e1.x + e1.y) + (e1.z + e1.w);
    #pragma unroll
    for (int o = 32; o > 0; o >>= 1) sum += __shfl_xor(sum, o);
    float inv = 1.0f / sum;
    e0.x *= inv; e0.y *= inv; e0.z *= inv; e0.w *= inv;
    e1.x *= inv; e1.y *= inv; e1.z *= inv; e1.w *= inv;
    *(float4*)&d[lane * 4] = e0;
    *(float4*)&d[256 + lane * 4] = e1;
}

// ---------------- output matmuls (bf16 MFMA, K-split staging for 2 blocks/CU) ----------------
// R7 post-mortem: full-K LDS (130 KB) -> 1 block/CU -> 1 wave/SIMD; staging latency and
// lgkm waits fully exposed. Fix: stage K in two 256-deep halves (Wt/Vt 64x264 bf16 =
// 68 KB total) -> 2 blocks/CU, 2 waves/SIMD; one block's staging overlaps the other's
// MFMA. Same verified fragment layout as R6/R7.
typedef __attribute__((ext_vector_type(8))) short bf16x8;
typedef __attribute__((ext_vector_type(4))) float f32x4;

__device__ __forceinline__ unsigned short f2bf(float f) {
    unsigned u = __float_as_uint(f);
    u += 0x7fffu + ((u >> 16) & 1u);          // round-to-nearest-even
    return (unsigned short)(u >> 16);
}
__device__ __forceinline__ unsigned pk2bf(float a, float b) {
    return (unsigned)f2bf(a) | ((unsigned)f2bf(b) << 16);
}

#define KT 264   // 256 + 8 pad (bf16); 528 B row stride, 16B-aligned, rows spread 4 banks

__global__ __launch_bounds__(256) void out_matmul(
    const float* __restrict__ w2m, const float* __restrict__ w1m,
    const float* __restrict__ v2,  const float* __restrict__ v1,
    float* __restrict__ o2, float* __restrict__ o1)
{
    __shared__ unsigned short Wt[64 * KT];
    __shared__ unsigned short Vt[64 * KT];
    int z = blockIdx.z; int b = z >> 1, m = z & 1;
    const float* Wm = (m ? w1m : w2m) + (size_t)b * NL1 * NL2;
    const float* Vm = (m ? v1 : v2)   + (size_t)b * NL2 * NV;
    float*       Om = (m ? o1 : o2)   + (size_t)b * NL1 * NV;
    int r0 = blockIdx.y * 64, d0 = blockIdx.x * 64;
    int tid = threadIdx.x;
    int lane = tid & 63, wid = tid >> 6;
    int wy = wid >> 1, wx = wid & 1;
    int lm = lane & 15, kg = lane >> 4;

    const unsigned short* Wlo = &Wt[(wy * 32 + lm) * KT];
    const unsigned short* Whi = Wlo + 16 * KT;
    const unsigned short* Vlo = &Vt[(wx * 32 + lm) * KT];
    const unsigned short* Vhi = Vlo + 16 * KT;

    f32x4 acc00 = {0.f,0.f,0.f,0.f}, acc01 = {0.f,0.f,0.f,0.f};
    f32x4 acc10 = {0.f,0.f,0.f,0.f}, acc11 = {0.f,0.f,0.f,0.f};

    for (int h = 0; h < 2; h++) {
        if (h) __syncthreads();                  // all waves done reading previous half
        int sbase = h * 256;
        // stage W half: coalesced (lanes span 512B contiguous per row)
        {
            int wr = tid >> 5, wc = tid & 31;
            #pragma unroll
            for (int p = 0; p < 8; p++) {
                int r = wr + 8 * p;
                const float* src = Wm + (size_t)(r0 + r) * 512 + sbase;
                unsigned short* dstrow = &Wt[r * KT];
                #pragma unroll
                for (int k = 0; k < 2; k++) {
                    int s = 4 * (wc + 32 * k);
                    float4 f = *(const float4*)&src[s];
                    *(unsigned*)&dstrow[s]     = pk2bf(f.x, f.y);
                    *(unsigned*)&dstrow[s + 2] = pk2bf(f.z, f.w);
                }
            }
        }
        // stage V half transposed: Vt[d][s] = bf16(V[sbase+s][d0+d])
        {
            int tm = tid & 15, tg = tid >> 4;
            #pragma unroll 4
            for (int u = 0; u < 8; u++) {
                int s = 2 * tg + 32 * u;
                #pragma unroll
                for (int j = 0; j < 4; j++) {
                    int d = tm + 16 * j;
                    float f0 = Vm[(size_t)(sbase + s) * NV + d0 + d];
                    float f1 = Vm[(size_t)(sbase + s + 1) * NV + d0 + d];
                    *(unsigned*)&Vt[d * KT + s] = pk2bf(f0, f1);
                }
            }
        }
        __syncthreads();
        #pragma unroll 4
        for (int t = 0; t < 8; t++) {
            int s0 = t * 32 + 8 * kg;
            bf16x8 fa0 = *(const bf16x8*)(Wlo + s0);
            bf16x8 fa1 = *(const bf16x8*)(Whi + s0);
            bf16x8 fb0 = *(const bf16x8*)(Vlo + s0);
            bf16x8 fb1 = *(const bf16x8*)(Vhi + s0);
            acc00 = __builtin_amdgcn_mfma_f32_16x16x32_bf16(fa0, fb0, acc00, 0, 0, 0);
            acc01 = __builtin_amdgcn_mfma_f32_16x16x32_bf16(fa0, fb1, acc01, 0, 0, 0);
            acc10 = __builtin_amdgcn_mfma_f32_16x16x32_bf16(fa1, fb0, acc10, 0, 0, 0);
            acc11 = __builtin_amdgcn_mfma_f32_16x16x32_bf16(fa1, fb1, acc11, 0, 0, 0);
        }
    }

    int rlo = r0 + wy * 32 + 4 * kg;
    int clo = d0 + wx * 32 + lm;
    #pragma unroll
    for (int e = 0; e < 4; e++) {
        Om[(size_t)(rlo + e) * NV + clo]           = acc00[e];
        Om[(size_t)(rlo + e) * NV + clo + 16]      = acc01[e];
        Om[(size_t)(rlo + 16 + e) * NV + clo]      = acc10[e];
        Om[(size_t)(rlo + 16 + e) * NV + clo + 16] = acc11[e];
    }
}

extern "C" void kernel_launch(void* const* d_in, const int* in_sizes, int n_in,
                              void* d_out, int out_size, void* d_ws, size_t ws_size,
                              hipStream_t stream) {
    const float* k1  = (const float*)d_in[0];
    const float* k2  = (const float*)d_in[1];
    const float* v1  = (const float*)d_in[2];
    const float* v2  = (const float*)d_in[3];
    const float* W1  = (const float*)d_in[4];
    const float* b1  = (const float*)d_in[5];
    const float* W2  = (const float*)d_in[6];
    const float* b2  = (const float*)d_in[7];
    const float* wsv = (const float*)d_in[8];
    const float* bsp = (const float*)d_in[9];
    const int* len1  = (const int*)d_in[10];
    const int* len2  = (const int*)d_in[11];

    float* out   = (float*)d_out;
    float* o1    = out + O1_OFF;
    float* o2    = out + O2_OFF;
    float* w1    = out + W1_OFF;
    float* w2    = out + W2_OFF;
    float* score = out + SC_OFF;

    float* p1    = (float*)d_ws;           // B*L1*A floats (pre-scaled)
    float* p2    = p1 + NB*NL1*NA;         // B*L2*A floats (pre-scaled)

    proj_kernel<<<dim3((NB*NL1)/4 + (NB*NL2)/4), 128, 0, stream>>>(k1, k2, W1, b1, W2, b2, p1, p2);
    score_kernel<<<dim3(NL2/32, NL1/32, NB), 256, 0, stream>>>(p1, p2, wsv, bsp, len1, len2, score, w1);
    softmax_both<<<dim3((NB*NL1 + NB*NL2)/4), 256, 0, stream>>>(score, w2, w1);
    out_matmul<<<dim3(NV/64, NL1/64, NB*2), 256, 0, stream>>>(w2, w1, v2, v1, o2, o1);
}

// Round 9
// 71.798 us; speedup vs baseline: 1.4162x; 1.0008x over previous
//
#include <hip/hip_runtime.h>
#include <math.h>

#define NB 4
#define NL1 512
#define NL2 512
#define NKD 256
#define NA 128
#define NV 256

// output layout (floats): o1 [B,L2,V], o2 [B,L1,V], w1 [B,L2,L1], w2 [B,L1,L2], score [B,L1,L2]
#define O1_OFF 0
#define O2_OFF (NB*NL2*NV)                 // 524288
#define W1_OFF (O2_OFF + NB*NL1*NV)        // 1048576
#define W2_OFF (W1_OFF + NB*NL2*NL1)       // 2097152
#define SC_OFF (W2_OFF + NB*NL1*NL2)       // 3145728

// masked score positions use -1e30f, NOT -inf (harness absmax: (-inf)-(-inf)=nan fails).
#define MASK_NEG (-1e30f)

// p1/p2 are pre-scaled by 2*log2(e) so e^{2z} = 2^{p1'+p2'}
#define SC2LOG2E 2.8853900817779268f

#if __has_builtin(__builtin_amdgcn_exp2f)
#define EXP2F(x) __builtin_amdgcn_exp2f(x)
#else
#define EXP2F(x) __expf((x) * 0.6931471805599453f)
#endif
#if __has_builtin(__builtin_amdgcn_rcpf)
#define RCPF(x) __builtin_amdgcn_rcpf(x)
#else
#define RCPF(x) (1.0f / (x))
#endif

// ---------------- projection: p = SC2LOG2E * (K @ W + b) ----------------
__global__ __launch_bounds__(128) void proj_kernel(
    const float* __restrict__ k1, const float* __restrict__ k2,
    const float* __restrict__ W1, const float* __restrict__ b1,
    const float* __restrict__ W2, const float* __restrict__ b2,
    float* __restrict__ p1, float* __restrict__ p2)
{
    __shared__ float kr[4][NKD];
    int blk = blockIdx.x;
    int tid = threadIdx.x;
    const float *K, *W, *bias; float* P; int rowbase;
    if (blk < (NB*NL1)/4) { K = k1; W = W1; bias = b1; P = p1; rowbase = blk*4; }
    else                  { K = k2; W = W2; bias = b2; P = p2; rowbase = (blk - (NB*NL1)/4)*4; }
    for (int idx = tid; idx < 256; idx += 128) {
        int r = idx >> 6, c = idx & 63;
        *(float4*)&kr[r][c*4] = *(const float4*)&K[(rowbase + r)*NKD + c*4];
    }
    __syncthreads();
    int a = tid;
    float acc0 = bias[a], acc1 = bias[a], acc2 = bias[a], acc3 = bias[a];
    #pragma unroll 4
    for (int k = 0; k < NKD; k++) {
        float wv = W[k*NA + a];
        acc0 = fmaf(kr[0][k], wv, acc0);
        acc1 = fmaf(kr[1][k], wv, acc1);
        acc2 = fmaf(kr[2][k], wv, acc2);
        acc3 = fmaf(kr[3][k], wv, acc3);
    }
    P[(rowbase+0)*NA + a] = acc0 * SC2LOG2E;
    P[(rowbase+1)*NA + a] = acc1 * SC2LOG2E;
    P[(rowbase+2)*NA + a] = acc2 * SC2LOG2E;
    P[(rowbase+3)*NA + a] = acc3 * SC2LOG2E;
}

// ---------------- score ----------------
#define P1_STRIDE 132
#define P2_STRIDE 36

#define TERM(acc, wv, xv, yv) acc = fmaf((wv), RCPF(1.0f + EXP2F((xv)+(yv))), (acc))

__global__ __launch_bounds__(256) void score_kernel(
    const float* __restrict__ p1, const float* __restrict__ p2,
    const float* __restrict__ ws, const float* __restrict__ bs,
    const int* __restrict__ len1, const int* __restrict__ len2,
    float* __restrict__ score, float* __restrict__ w1pre)
{
    __shared__ float p1t[32][P1_STRIDE];
    __shared__ float p2t[NA][P2_STRIDE];
    __shared__ float wst[NA];
    __shared__ float wsum[2];
    __shared__ float tile[32][33];
    int b  = blockIdx.z;
    int i0 = blockIdx.y * 32, j0 = blockIdx.x * 32;
    int tid = threadIdx.x;
    if (tid < 128) {
        float w = ws[tid];
        wst[tid] = -2.0f * w;
        float v = w;
        #pragma unroll
        for (int o = 32; o > 0; o >>= 1) v += __shfl_xor(v, o);
        if ((tid & 63) == 0) wsum[tid >> 6] = v;
    }
    const float* p1src = p1 + (b*NL1 + i0)*NA;
    const float* p2src = p2 + (b*NL2 + j0)*NA;
    for (int idx = tid; idx < 1024; idx += 256) {
        int r = idx >> 5, c = idx & 31;
        *(float4*)&p1t[r][c*4] = *(const float4*)&p1src[r*NA + c*4];
    }
    for (int idx = tid; idx < 1024; idx += 256) {
        int j = idx >> 5, c = idx & 31;
        float4 t = *(const float4*)&p2src[j*NA + c*4];
        p2t[c*4+0][j] = t.x; p2t[c*4+1][j] = t.y;
        p2t[c*4+2][j] = t.z; p2t[c*4+3][j] = t.w;
    }
    __syncthreads();

    int tx = tid & 15, ty = tid >> 4;
    int il = ty*2, jl = tx*2;
    float acc00 = 0.f, acc01 = 0.f, acc10 = 0.f, acc11 = 0.f;
    #pragma unroll 2
    for (int a = 0; a < NA; a += 4) {
        float4 wv = *(float4*)&wst[a];
        float4 x0 = *(float4*)&p1t[il  ][a];
        float4 x1 = *(float4*)&p1t[il+1][a];
        float2 y0 = *(float2*)&p2t[a  ][jl];
        float2 y1 = *(float2*)&p2t[a+1][jl];
        float2 y2 = *(float2*)&p2t[a+2][jl];
        float2 y3 = *(float2*)&p2t[a+3][jl];
        TERM(acc00, wv.x, x0.x, y0.x); TERM(acc01, wv.x, x0.x, y0.y);
        TERM(acc10, wv.x, x1.x, y0.x); TERM(acc11, wv.x, x1.x, y0.y);
        TERM(acc00, wv.y, x0.y, y1.x); TERM(acc01, wv.y, x0.y, y1.y);
        TERM(acc10, wv.y, x1.y, y1.x); TERM(acc11, wv.y, x1.y, y1.y);
        TERM(acc00, wv.z, x0.z, y2.x); TERM(acc01, wv.z, x0.z, y2.y);
        TERM(acc10, wv.z, x1.z, y2.x); TERM(acc11, wv.z, x1.z, y2.y);
        TERM(acc00, wv.w, x0.w, y3.x); TERM(acc01, wv.w, x0.w, y3.y);
        TERM(acc10, wv.w, x1.w, y3.x); TERM(acc11, wv.w, x1.w, y3.y);
    }
    float sb = wsum[0] + wsum[1] + bs[0];
    int n1 = len1[b], n2 = len2[b];
    float accs[2][2] = {{acc00, acc01}, {acc10, acc11}};
    #pragma unroll
    for (int di = 0; di < 2; di++) {
        #pragma unroll
        for (int dj = 0; dj < 2; dj++) {
            int gi = i0 + il + di, gj = j0 + jl + dj;
            float v = accs[di][dj] + sb;
            int rp = (gi >= n1), cp = (gj >= n2);
            if (rp + cp == 1) v = MASK_NEG;
            score[(b*NL1 + gi)*NL2 + gj] = v;
            tile[il + di][jl + dj] = v;   // local [i][j]
        }
    }
    __syncthreads();
    #pragma unroll
    for (int di = 0; di < 2; di++) {
        int rr = il + di;  // local j
        float2 t = make_float2(tile[jl][rr], tile[jl+1][rr]);
        *(float2*)&w1pre[((size_t)b*NL2 + j0 + rr)*NL1 + i0 + jl] = t;
    }
}

// ---------------- merged softmax: one WAVE per row, no LDS, no barriers ----------------
__global__ __launch_bounds__(256) void softmax_both(const float* __restrict__ score,
                                                    float* __restrict__ w2,
                                                    float* __restrict__ w1)
{
    int row = blockIdx.x * 4 + (threadIdx.x >> 6);
    int lane = threadIdx.x & 63;
    const float* s; float* d;
    if (row < NB*NL1) { s = score + (size_t)row * NL2; d = w2 + (size_t)row * NL2; }
    else { size_t r = row - NB*NL1; s = w1 + r * NL1; d = w1 + r * NL1; }
    float4 v0 = *(const float4*)&s[lane * 4];
    float4 v1 = *(const float4*)&s[256 + lane * 4];
    float m = fmaxf(fmaxf(fmaxf(v0.x, v0.y), fmaxf(v0.z, v0.w)),
                    fmaxf(fmaxf(v1.x, v1.y), fmaxf(v1.z, v1.w)));
    #pragma unroll
    for (int o = 32; o > 0; o >>= 1) m = fmaxf(m, __shfl_xor(m, o));
    float4 e0, e1;
    e0.x = __expf(v0.x - m); e0.y = __expf(v0.y - m);
    e0.z = __expf(v0.z - m); e0.w = __expf(v0.w - m);
    e1.x = __expf(v1.x - m); e1.y = __expf(v1.y - m);
    e1.z = __expf(v1.z - m); e1.w = __expf(v1.w - m);
    float sum = (e0.x + e0.y) + (e0.z + e0.w) + (e1.x + e1.y) + (e1.z + e1.w);
    #pragma unroll
    for (int o = 32; o > 0; o >>= 1) sum += __shfl_xor(sum, o);
    float inv = 1.0f / sum;
    e0.x *= inv; e0.y *= inv; e0.z *= inv; e0.w *= inv;
    e1.x *= inv; e1.y *= inv; e1.z *= inv; e1.w *= inv;
    *(float4*)&d[lane * 4] = e0;
    *(float4*)&d[256 + lane * 4] = e1;
}

// ---------------- output matmuls (bf16 MFMA, 8 waves -> 2 waves/SIMD intra-block) ----------------
// R8 post-mortem: grid==CU count, so the K-split's "2 blocks/CU" never materialized;
// still 1 wave/SIMD. Fix: 512 threads = 8 waves on the single resident block ->
// 2 waves/SIMD guaranteed. 8 waves = 4 row-blocks x 2 col-blocks; each wave computes
// a 16x32 strip (1 A-frag + 2 B-frags + 2 MFMA per K-step). Per-wave staging halves;
// lgkm waits covered by the co-resident wave. K-split staging (68 KB) as R8.
typedef __attribute__((ext_vector_type(8))) short bf16x8;
typedef __attribute__((ext_vector_type(4))) float f32x4;

__device__ __forceinline__ unsigned short f2bf(float f) {
    unsigned u = __float_as_uint(f);
    u += 0x7fffu + ((u >> 16) & 1u);          // round-to-nearest-even
    return (unsigned short)(u >> 16);
}
__device__ __forceinline__ unsigned pk2bf(float a, float b) {
    return (unsigned)f2bf(a) | ((unsigned)f2bf(b) << 16);
}

#define KT 264   // 256 + 8 pad (bf16); 528 B row stride, 16B-aligned

__global__ __launch_bounds__(512) void out_matmul(
    const float* __restrict__ w2m, const float* __restrict__ w1m,
    const float* __restrict__ v2,  const float* __restrict__ v1,
    float* __restrict__ o2, float* __restrict__ o1)
{
    __shared__ unsigned short Wt[64 * KT];
    __shared__ unsigned short Vt[64 * KT];
    int z = blockIdx.z; int b = z >> 1, m = z & 1;
    const float* Wm = (m ? w1m : w2m) + (size_t)b * NL1 * NL2;
    const float* Vm = (m ? v1 : v2)   + (size_t)b * NL2 * NV;
    float*       Om = (m ? o1 : o2)   + (size_t)b * NL1 * NV;
    int r0 = blockIdx.y * 64, d0 = blockIdx.x * 64;
    int tid = threadIdx.x;                 // 0..511
    int lane = tid & 63, wid = tid >> 6;   // 8 waves
    int ry = wid & 3, cx = wid >> 2;       // 4 row-blocks x 2 col-blocks
    int lm = lane & 15, kg = lane >> 4;

    const unsigned short* Wf  = &Wt[(ry * 16 + lm) * KT];
    const unsigned short* Vlo = &Vt[(cx * 32 + lm) * KT];
    const unsigned short* Vhi = Vlo + 16 * KT;

    f32x4 acc0 = {0.f,0.f,0.f,0.f}, acc1 = {0.f,0.f,0.f,0.f};

    for (int h = 0; h < 2; h++) {
        if (h) __syncthreads();                  // all waves done reading previous half
        int sbase = h * 256;
        // stage W half: row tid>>3 (0..63), 128B chunk tid&7 -> 8 float4/thread
        {
            int wr = tid >> 3, wc = tid & 7;
            const float* src = Wm + (size_t)(r0 + wr) * 512 + sbase + wc * 32;
            unsigned short* dst = &Wt[wr * KT + wc * 32];
            #pragma unroll
            for (int k = 0; k < 8; k++) {
                float4 f = *(const float4*)&src[k * 4];
                *(unsigned*)&dst[k * 4]     = pk2bf(f.x, f.y);
                *(unsigned*)&dst[k * 4 + 2] = pk2bf(f.z, f.w);
            }
        }
        // stage V half transposed: Vt[d][s] = bf16(V[sbase+s][d0+d]); 32 floats/thread
        {
            int tm = tid & 15, tg = tid >> 4;    // tg 0..31
            #pragma unroll
            for (int u = 0; u < 4; u++) {
                int s = 2 * tg + 64 * u;
                #pragma unroll
                for (int j = 0; j < 4; j++) {
                    int d = tm + 16 * j;
                    float f0 = Vm[(size_t)(sbase + s) * NV + d0 + d];
                    float f1 = Vm[(size_t)(sbase + s + 1) * NV + d0 + d];
                    *(unsigned*)&Vt[d * KT + s] = pk2bf(f0, f1);
                }
            }
        }
        __syncthreads();
        #pragma unroll 4
        for (int t = 0; t < 8; t++) {
            int s0 = t * 32 + 8 * kg;
            bf16x8 fa  = *(const bf16x8*)(Wf  + s0);
            bf16x8 fb0 = *(const bf16x8*)(Vlo + s0);
            bf16x8 fb1 = *(const bf16x8*)(Vhi + s0);
            acc0 = __builtin_amdgcn_mfma_f32_16x16x32_bf16(fa, fb0, acc0, 0, 0, 0);
            acc1 = __builtin_amdgcn_mfma_f32_16x16x32_bf16(fa, fb1, acc1, 0, 0, 0);
        }
    }

    int rlo = r0 + ry * 16 + 4 * kg;
    int clo = d0 + cx * 32 + lm;
    #pragma unroll
    for (int e = 0; e < 4; e++) {
        Om[(size_t)(rlo + e) * NV + clo]      = acc0[e];
        Om[(size_t)(rlo + e) * NV + clo + 16] = acc1[e];
    }
}

extern "C" void kernel_launch(void* const* d_in, const int* in_sizes, int n_in,
                              void* d_out, int out_size, void* d_ws, size_t ws_size,
                              hipStream_t stream) {
    const float* k1  = (const float*)d_in[0];
    const float* k2  = (const float*)d_in[1];
    const float* v1  = (const float*)d_in[2];
    const float* v2  = (const float*)d_in[3];
    const float* W1  = (const float*)d_in[4];
    const float* b1  = (const float*)d_in[5];
    const float* W2  = (const float*)d_in[6];
    const float* b2  = (const float*)d_in[7];
    const float* wsv = (const float*)d_in[8];
    const float* bsp = (const float*)d_in[9];
    const int* len1  = (const int*)d_in[10];
    const int* len2  = (const int*)d_in[11];

    float* out   = (float*)d_out;
    float* o1    = out + O1_OFF;
    float* o2    = out + O2_OFF;
    float* w1    = out + W1_OFF;
    float* w2    = out + W2_OFF;
    float* score = out + SC_OFF;

    float* p1    = (float*)d_ws;           // B*L1*A floats (pre-scaled)
    float* p2    = p1 + NB*NL1*NA;         // B*L2*A floats (pre-scaled)

    proj_kernel<<<dim3((NB*NL1)/4 + (NB*NL2)/4), 128, 0, stream>>>(k1, k2, W1, b1, W2, b2, p1, p2);
    score_kernel<<<dim3(NL2/32, NL1/32, NB), 256, 0, stream>>>(p1, p2, wsv, bsp, len1, len2, score, w1);
    softmax_both<<<dim3((NB*NL1 + NB*NL2)/4), 256, 0, stream>>>(score, w2, w1);
    out_matmul<<<dim3(NV/64, NL1/64, NB*2), 512, 0, stream>>>(w2, w1, v2, v1, o2, o1);
}

// Round 10
// 62.135 us; speedup vs baseline: 1.6365x; 1.1555x over previous
//
#include <hip/hip_runtime.h>
#include <math.h>

#define NB 4
#define NL1 512
#define NL2 512
#define NKD 256
#define NA 128
#define NV 256

// output layout (floats): o1 [B,L2,V], o2 [B,L1,V], w1 [B,L2,L1], w2 [B,L1,L2], score [B,L1,L2]
#define O1_OFF 0
#define O2_OFF (NB*NL2*NV)                 // 524288
#define W1_OFF (O2_OFF + NB*NL1*NV)        // 1048576
#define W2_OFF (W1_OFF + NB*NL2*NL1)       // 2097152
#define SC_OFF (W2_OFF + NB*NL1*NL2)       // 3145728

// masked score positions use -1e30f, NOT -inf (harness absmax: (-inf)-(-inf)=nan fails).
#define MASK_NEG (-1e30f)

// p1/p2 are pre-scaled by 2*log2(e) so e^{2z} = 2^{p1'+p2'}; we then store
// E = 2^clamp(p',±50) so score needs only a MUL + RCP per term (2^x·2^y = 2^(x+y)).
#define SC2LOG2E 2.8853900817779268f

#if __has_builtin(__builtin_amdgcn_exp2f)
#define EXP2F(x) __builtin_amdgcn_exp2f(x)
#else
#define EXP2F(x) __expf((x) * 0.6931471805599453f)
#endif
#if __has_builtin(__builtin_amdgcn_rcpf)
#define RCPF(x) __builtin_amdgcn_rcpf(x)
#else
#define RCPF(x) (1.0f / (x))
#endif

// ---------------- projection: E = 2^clamp(SC2LOG2E*(K @ W + b), ±50) ----------------
// Exp hoisted out of score (2^x*2^y=2^(x+y)): 0.5M exp here vs 134M there.
// Clamp ±50: E in [2^-50,2^50], products in [7.9e-31,1.3e30] -> no inf/NaN;
// denormal product flushes to 0 -> rcp(1)=1 = tanh saturation limit (correct).
__global__ __launch_bounds__(128) void proj_kernel(
    const float* __restrict__ k1, const float* __restrict__ k2,
    const float* __restrict__ W1, const float* __restrict__ b1,
    const float* __restrict__ W2, const float* __restrict__ b2,
    float* __restrict__ p1, float* __restrict__ p2)
{
    __shared__ float kr[4][NKD];
    int blk = blockIdx.x;
    int tid = threadIdx.x;
    const float *K, *W, *bias; float* P; int rowbase;
    if (blk < (NB*NL1)/4) { K = k1; W = W1; bias = b1; P = p1; rowbase = blk*4; }
    else                  { K = k2; W = W2; bias = b2; P = p2; rowbase = (blk - (NB*NL1)/4)*4; }
    for (int idx = tid; idx < 256; idx += 128) {
        int r = idx >> 6, c = idx & 63;
        *(float4*)&kr[r][c*4] = *(const float4*)&K[(rowbase + r)*NKD + c*4];
    }
    __syncthreads();
    int a = tid;
    float acc0 = bias[a], acc1 = bias[a], acc2 = bias[a], acc3 = bias[a];
    #pragma unroll 4
    for (int k = 0; k < NKD; k++) {
        float wv = W[k*NA + a];
        acc0 = fmaf(kr[0][k], wv, acc0);
        acc1 = fmaf(kr[1][k], wv, acc1);
        acc2 = fmaf(kr[2][k], wv, acc2);
        acc3 = fmaf(kr[3][k], wv, acc3);
    }
    float s0 = fminf(fmaxf(acc0 * SC2LOG2E, -50.f), 50.f);
    float s1 = fminf(fmaxf(acc1 * SC2LOG2E, -50.f), 50.f);
    float s2 = fminf(fmaxf(acc2 * SC2LOG2E, -50.f), 50.f);
    float s3 = fminf(fmaxf(acc3 * SC2LOG2E, -50.f), 50.f);
    P[(rowbase+0)*NA + a] = EXP2F(s0);
    P[(rowbase+1)*NA + a] = EXP2F(s1);
    P[(rowbase+2)*NA + a] = EXP2F(s2);
    P[(rowbase+3)*NA + a] = EXP2F(s3);
}

// ---------------- score ----------------
// score[b,i,j] = swsbs + sum_a ws2[a] * rcp(1 + E1[i][a]*E2[j][a]), masked.
// One trans op (rcp) per term; 1+E1*E2 fused into a single FMA.
#define P1_STRIDE 132
#define P2_STRIDE 36

#define TERM(acc, wv, xv, yv) acc = fmaf((wv), RCPF(fmaf((xv), (yv), 1.0f)), (acc))

__global__ __launch_bounds__(256) void score_kernel(
    const float* __restrict__ p1, const float* __restrict__ p2,
    const float* __restrict__ ws, const float* __restrict__ bs,
    const int* __restrict__ len1, const int* __restrict__ len2,
    float* __restrict__ score, float* __restrict__ w1pre)
{
    __shared__ float p1t[32][P1_STRIDE];
    __shared__ float p2t[NA][P2_STRIDE];
    __shared__ float wst[NA];
    __shared__ float wsum[2];
    __shared__ float tile[32][33];
    int b  = blockIdx.z;
    int i0 = blockIdx.y * 32, j0 = blockIdx.x * 32;
    int tid = threadIdx.x;
    if (tid < 128) {
        float w = ws[tid];
        wst[tid] = -2.0f * w;
        float v = w;
        #pragma unroll
        for (int o = 32; o > 0; o >>= 1) v += __shfl_xor(v, o);
        if ((tid & 63) == 0) wsum[tid >> 6] = v;
    }
    const float* p1src = p1 + (b*NL1 + i0)*NA;
    const float* p2src = p2 + (b*NL2 + j0)*NA;
    for (int idx = tid; idx < 1024; idx += 256) {
        int r = idx >> 5, c = idx & 31;
        *(float4*)&p1t[r][c*4] = *(const float4*)&p1src[r*NA + c*4];
    }
    for (int idx = tid; idx < 1024; idx += 256) {
        int j = idx >> 5, c = idx & 31;
        float4 t = *(const float4*)&p2src[j*NA + c*4];
        p2t[c*4+0][j] = t.x; p2t[c*4+1][j] = t.y;
        p2t[c*4+2][j] = t.z; p2t[c*4+3][j] = t.w;
    }
    __syncthreads();

    int tx = tid & 15, ty = tid >> 4;
    int il = ty*2, jl = tx*2;
    float acc00 = 0.f, acc01 = 0.f, acc10 = 0.f, acc11 = 0.f;
    #pragma unroll 2
    for (int a = 0; a < NA; a += 4) {
        float4 wv = *(float4*)&wst[a];
        float4 x0 = *(float4*)&p1t[il  ][a];
        float4 x1 = *(float4*)&p1t[il+1][a];
        float2 y0 = *(float2*)&p2t[a  ][jl];
        float2 y1 = *(float2*)&p2t[a+1][jl];
        float2 y2 = *(float2*)&p2t[a+2][jl];
        float2 y3 = *(float2*)&p2t[a+3][jl];
        TERM(acc00, wv.x, x0.x, y0.x); TERM(acc01, wv.x, x0.x, y0.y);
        TERM(acc10, wv.x, x1.x, y0.x); TERM(acc11, wv.x, x1.x, y0.y);
        TERM(acc00, wv.y, x0.y, y1.x); TERM(acc01, wv.y, x0.y, y1.y);
        TERM(acc10, wv.y, x1.y, y1.x); TERM(acc11, wv.y, x1.y, y1.y);
        TERM(acc00, wv.z, x0.z, y2.x); TERM(acc01, wv.z, x0.z, y2.y);
        TERM(acc10, wv.z, x1.z, y2.x); TERM(acc11, wv.z, x1.z, y2.y);
        TERM(acc00, wv.w, x0.w, y3.x); TERM(acc01, wv.w, x0.w, y3.y);
        TERM(acc10, wv.w, x1.w, y3.x); TERM(acc11, wv.w, x1.w, y3.y);
    }
    float sb = wsum[0] + wsum[1] + bs[0];
    int n1 = len1[b], n2 = len2[b];
    float accs[2][2] = {{acc00, acc01}, {acc10, acc11}};
    #pragma unroll
    for (int di = 0; di < 2; di++) {
        #pragma unroll
        for (int dj = 0; dj < 2; dj++) {
            int gi = i0 + il + di, gj = j0 + jl + dj;
            float v = accs[di][dj] + sb;
            int rp = (gi >= n1), cp = (gj >= n2);
            if (rp + cp == 1) v = MASK_NEG;
            score[(b*NL1 + gi)*NL2 + gj] = v;
            tile[il + di][jl + dj] = v;   // local [i][j]
        }
    }
    __syncthreads();
    #pragma unroll
    for (int di = 0; di < 2; di++) {
        int rr = il + di;  // local j
        float2 t = make_float2(tile[jl][rr], tile[jl+1][rr]);
        *(float2*)&w1pre[((size_t)b*NL2 + j0 + rr)*NL1 + i0 + jl] = t;
    }
}

// ---------------- merged softmax: one WAVE per row, no LDS, no barriers ----------------
__global__ __launch_bounds__(256) void softmax_both(const float* __restrict__ score,
                                                    float* __restrict__ w2,
                                                    float* __restrict__ w1)
{
    int row = blockIdx.x * 4 + (threadIdx.x >> 6);
    int lane = threadIdx.x & 63;
    const float* s; float* d;
    if (row < NB*NL1) { s = score + (size_t)row * NL2; d = w2 + (size_t)row * NL2; }
    else { size_t r = row - NB*NL1; s = w1 + r * NL1; d = w1 + r * NL1; }
    float4 v0 = *(const float4*)&s[lane * 4];
    float4 v1 = *(const float4*)&s[256 + lane * 4];
    float m = fmaxf(fmaxf(fmaxf(v0.x, v0.y), fmaxf(v0.z, v0.w)),
                    fmaxf(fmaxf(v1.x, v1.y), fmaxf(v1.z, v1.w)));
    #pragma unroll
    for (int o = 32; o > 0; o >>= 1) m = fmaxf(m, __shfl_xor(m, o));
    float4 e0, e1;
    e0.x = __expf(v0.x - m); e0.y = __expf(v0.y - m);
    e0.z = __expf(v0.z - m); e0.w = __expf(v0.w - m);
    e1.x = __expf(v1.x - m); e1.y = __expf(v1.y - m);
    e1.z = __expf(v1.z - m); e1.w = __expf(v1.w - m);
    float sum = (e0.x + e0.y) + (e0.z + e0.w) + (e1.x + e1.y) + (e1.z + e1.w);
    #pragma unroll
    for (int o = 32; o > 0; o >>= 1) sum += __shfl_xor(sum, o);
    float inv = 1.0f / sum;
    e0.x *= inv; e0.y *= inv; e0.z *= inv; e0.w *= inv;
    e1.x *= inv; e1.y *= inv; e1.z *= inv; e1.w *= inv;
    *(float4*)&d[lane * 4] = e0;
    *(float4*)&d[256 + lane * 4] = e1;
}

// ---------------- output matmuls (bf16 MFMA, 8 waves, K-split staging) ----------------
typedef __attribute__((ext_vector_type(8))) short bf16x8;
typedef __attribute__((ext_vector_type(4))) float f32x4;

__device__ __forceinline__ unsigned short f2bf(float f) {
    unsigned u = __float_as_uint(f);
    u += 0x7fffu + ((u >> 16) & 1u);          // round-to-nearest-even
    return (unsigned short)(u >> 16);
}
__device__ __forceinline__ unsigned pk2bf(float a, float b) {
    return (unsigned)f2bf(a) | ((unsigned)f2bf(b) << 16);
}

#define KT 264   // 256 + 8 pad (bf16); 528 B row stride, 16B-aligned

__global__ __launch_bounds__(512) void out_matmul(
    const float* __restrict__ w2m, const float* __restrict__ w1m,
    const float* __restrict__ v2,  const float* __restrict__ v1,
    float* __restrict__ o2, float* __restrict__ o1)
{
    __shared__ unsigned short Wt[64 * KT];
    __shared__ unsigned short Vt[64 * KT];
    int z = blockIdx.z; int b = z >> 1, m = z & 1;
    const float* Wm = (m ? w1m : w2m) + (size_t)b * NL1 * NL2;
    const float* Vm = (m ? v1 : v2)   + (size_t)b * NL2 * NV;
    float*       Om = (m ? o1 : o2)   + (size_t)b * NL1 * NV;
    int r0 = blockIdx.y * 64, d0 = blockIdx.x * 64;
    int tid = threadIdx.x;                 // 0..511
    int lane = tid & 63, wid = tid >> 6;   // 8 waves
    int ry = wid & 3, cx = wid >> 2;       // 4 row-blocks x 2 col-blocks
    int lm = lane & 15, kg = lane >> 4;

    const unsigned short* Wf  = &Wt[(ry * 16 + lm) * KT];
    const unsigned short* Vlo = &Vt[(cx * 32 + lm) * KT];
    const unsigned short* Vhi = Vlo + 16 * KT;

    f32x4 acc0 = {0.f,0.f,0.f,0.f}, acc1 = {0.f,0.f,0.f,0.f};

    for (int h = 0; h < 2; h++) {
        if (h) __syncthreads();                  // all waves done reading previous half
        int sbase = h * 256;
        // stage W half: row tid>>3 (0..63), 128B chunk tid&7 -> 8 float4/thread
        {
            int wr = tid >> 3, wc = tid & 7;
            const float* src = Wm + (size_t)(r0 + wr) * 512 + sbase + wc * 32;
            unsigned short* dst = &Wt[wr * KT + wc * 32];
            #pragma unroll
            for (int k = 0; k < 8; k++) {
                float4 f = *(const float4*)&src[k * 4];
                *(unsigned*)&dst[k * 4]     = pk2bf(f.x, f.y);
                *(unsigned*)&dst[k * 4 + 2] = pk2bf(f.z, f.w);
            }
        }
        // stage V half transposed: Vt[d][s] = bf16(V[sbase+s][d0+d]); 32 floats/thread
        {
            int tm = tid & 15, tg = tid >> 4;    // tg 0..31
            #pragma unroll
            for (int u = 0; u < 4; u++) {
                int s = 2 * tg + 64 * u;
                #pragma unroll
                for (int j = 0; j < 4; j++) {
                    int d = tm + 16 * j;
                    float f0 = Vm[(size_t)(sbase + s) * NV + d0 + d];
                    float f1 = Vm[(size_t)(sbase + s + 1) * NV + d0 + d];
                    *(unsigned*)&Vt[d * KT + s] = pk2bf(f0, f1);
                }
            }
        }
        __syncthreads();
        #pragma unroll 4
        for (int t = 0; t < 8; t++) {
            int s0 = t * 32 + 8 * kg;
            bf16x8 fa  = *(const bf16x8*)(Wf  + s0);
            bf16x8 fb0 = *(const bf16x8*)(Vlo + s0);
            bf16x8 fb1 = *(const bf16x8*)(Vhi + s0);
            acc0 = __builtin_amdgcn_mfma_f32_16x16x32_bf16(fa, fb0, acc0, 0, 0, 0);
            acc1 = __builtin_amdgcn_mfma_f32_16x16x32_bf16(fa, fb1, acc1, 0, 0, 0);
        }
    }

    int rlo = r0 + ry * 16 + 4 * kg;
    int clo = d0 + cx * 32 + lm;
    #pragma unroll
    for (int e = 0; e < 4; e++) {
        Om[(size_t)(rlo + e) * NV + clo]      = acc0[e];
        Om[(size_t)(rlo + e) * NV + clo + 16] = acc1[e];
    }
}

extern "C" void kernel_launch(void* const* d_in, const int* in_sizes, int n_in,
                              void* d_out, int out_size, void* d_ws, size_t ws_size,
                              hipStream_t stream) {
    const float* k1  = (const float*)d_in[0];
    const float* k2  = (const float*)d_in[1];
    const float* v1  = (const float*)d_in[2];
    const float* v2  = (const float*)d_in[3];
    const float* W1  = (const float*)d_in[4];
    const float* b1  = (const float*)d_in[5];
    const float* W2  = (const float*)d_in[6];
    const float* b2  = (const float*)d_in[7];
    const float* wsv = (const float*)d_in[8];
    const float* bsp = (const float*)d_in[9];
    const int* len1  = (const int*)d_in[10];
    const int* len2  = (const int*)d_in[11];

    float* out   = (float*)d_out;
    float* o1    = out + O1_OFF;
    float* o2    = out + O2_OFF;
    float* w1    = out + W1_OFF;
    float* w2    = out + W2_OFF;
    float* score = out + SC_OFF;

    float* p1    = (float*)d_ws;           // B*L1*A floats (E1 = 2^p1')
    float* p2    = p1 + NB*NL1*NA;         // B*L2*A floats (E2 = 2^p2')

    proj_kernel<<<dim3((NB*NL1)/4 + (NB*NL2)/4), 128, 0, stream>>>(k1, k2, W1, b1, W2, b2, p1, p2);
    score_kernel<<<dim3(NL2/32, NL1/32, NB), 256, 0, stream>>>(p1, p2, wsv, bsp, len1, len2, score, w1);
    softmax_both<<<dim3((NB*NL1 + NB*NL2)/4), 256, 0, stream>>>(score, w2, w1);
    out_matmul<<<dim3(NV/64, NL1/64, NB*2), 512, 0, stream>>>(w2, w1, v2, v1, o2, o1);
}